// Round 10
// baseline (7286.613 us; speedup 1.0000x reference)
//
#include <hip/hip_runtime.h>
#include <hip/hip_bf16.h>
#include <stdint.h>

// LSTM decoder: H=1024, B=4096, T=128, IN=1.
// R10 = R7 base (BJ=64, BKK=64, conflict-free XOR swizzle, global_load_lds
// w16, vmcnt(0)+syncthreads staging) with:
//  - v_mfma_f32_32x32x16_bf16 (4060 vs 3378 FLOP/cyc, half the MFMA insts)
//  - Wr rows ordered [jb2][j-half][gate][jj32] so MFMA n-tile g == gate g
//  - XCD pinning 4 jb2 x 16 bb per XCD (W 2MB L2-resident, h dup 4x not 8x)

#define HH 1024
#define BB 4096
#define TT 128

#define BM 128   // batch rows per block
#define BKK 64   // K tile

typedef __bf16 bf16;
typedef __bf16 v8bf __attribute__((ext_vector_type(8)));
typedef float f32x16 __attribute__((ext_vector_type(16)));

__device__ __forceinline__ float fast_sigmoid(float x) {
    return 1.0f / (1.0f + __expf(-x));
}
__device__ __forceinline__ float fast_tanh(float x) {
    return 1.0f - 2.0f / (__expf(2.0f * x) + 1.0f);
}

__device__ __forceinline__ void gload_lds16(const void* g, void* l) {
    __builtin_amdgcn_global_load_lds(
        (const __attribute__((address_space(1))) uint32_t*)(uintptr_t)g,
        (__attribute__((address_space(3))) uint32_t*)(uint32_t)(uintptr_t)l,
        16, 0, 0);
}

// ---- Prologue kernels ------------------------------------------------------

// Wr row = jb2*256 + h*128 + g*32 + jj  <->  Whh row = g*HH + jb2*64 + h*32 + jj
__global__ void prep_weights(const float* __restrict__ Whh,
                             const float* __restrict__ bih,
                             const float* __restrict__ bhh,
                             bf16* __restrict__ Wr,
                             float* __restrict__ bias) {
    int idx = blockIdx.x * blockDim.x + threadIdx.x;
    if (idx < 4 * HH * HH) {
        int k   = idx & (HH - 1);
        int row = idx >> 10;
        int jb2 = row >> 8;
        int h   = (row >> 7) & 1;
        int g   = (row >> 5) & 3;
        int jj  = row & 31;
        int srow = g * HH + jb2 * 64 + h * 32 + jj;
        Wr[idx] = (bf16)Whh[srow * HH + k];
    }
    if (idx < 4 * HH) bias[idx] = bih[idx] + bhh[idx];
}

__global__ void prep_h(const float* __restrict__ h0, bf16* __restrict__ hb) {
    int idx = blockIdx.x * blockDim.x + threadIdx.x;
    if (idx < BB * HH) hb[idx] = (bf16)h0[idx];
}

__global__ void prep_pred(float* __restrict__ predbuf, const float* __restrict__ b_out) {
    int idx = blockIdx.x * blockDim.x + threadIdx.x;
    if (idx < (TT + 1) * BB) predbuf[idx] = (idx < BB) ? 0.0f : b_out[0];
}

// ---- Per-step fused GEMM + cell update ------------------------------------
// 512 blocks. Block tile: 128 batch x 256 weight rows (4 gates x 64 j).
// Wave (waveM, waveN): 64 batch x 128 wrows (= 4 gates x 32 j, j-half waveN).
// 32x32x16 MFMA tiles: acc[mi][g], mi = batch 32-tile, g = gate.
// C/D mapping (verified m74/m101): col(n,j) = lane&31,
//   row(m,batch) = (reg&3) + 8*(reg>>2) + 4*(lane>>5).

__global__ __launch_bounds__(256, 2)
void lstm_step(const bf16* __restrict__ hread, bf16* __restrict__ hwrite,
               const float* __restrict__ cin, float* __restrict__ cout,
               const bf16* __restrict__ Wr, const float* __restrict__ bias,
               const float* __restrict__ Wih, const float* __restrict__ Wout,
               const float* __restrict__ predbuf_r, float* __restrict__ predbuf_w) {
    // unpadded 128-B rows, XOR-swizzled: phys 16B-chunk = logical ^ (row&7)
    __shared__ bf16 As[BM][BKK];        // h tile: 128 x 64      (16 KB)
    __shared__ bf16 Bs[2 * BM][BKK];    // weights: 256 x 64     (32 KB)

    const int tid   = threadIdx.x;
    const int lane  = tid & 63;
    const int w     = tid >> 6;
    const int waveM = w >> 1, waveN = w & 1;
    const int l31   = lane & 31, l5 = lane >> 5;

    // XCD pinning: XCD x = bid&7 hosts jb2 in {4*(x>>1)..+3}, bb in
    // {(x&1)*16..+15}: W slice 2MB L2-resident, each h tile on 4 XCDs.
    const int bid = blockIdx.x;
    const int x8  = bid & 7;
    const int i64 = bid >> 3;
    const int jb2 = (x8 >> 1) * 4 + (i64 & 3);   // 0..15
    const int bb  = (x8 & 1) * 16 + (i64 >> 2);  // 0..31
    const int blockB = bb * BM;

    f32x16 acc[2][4]; // [batch 32-tile][gate]
#pragma unroll
    for (int mi = 0; mi < 2; mi++)
#pragma unroll
        for (int g = 0; g < 4; g++) acc[mi][g] = (f32x16)(0.0f);

    const bf16* Asrc = hread + (size_t)blockB * HH;
    const bf16* Bsrc = Wr + (size_t)jb2 * 256 * HH;

    const int r8  = lane >> 3;        // 0..7 (staging row-in-group)
    const int gc  = (lane & 7) ^ r8;  // staging swizzled global chunk
    const int swr = lane & 7;         // read-side swizzle key (row&7 = lane&7)

    for (int k0 = 0; k0 < HH; k0 += BKK) {
        // A: wave stages rows [w*32, w*32+32) — 4 calls (8 rows x 128 B each)
#pragma unroll
        for (int c2 = 0; c2 < 4; c2++) {
            const int rowb = w * 32 + c2 * 8;
            gload_lds16(Asrc + (size_t)(rowb + r8) * HH + k0 + gc * 8, &As[rowb][0]);
        }
        // B: wave stages rows [w*64, w*64+64) — 8 calls
#pragma unroll
        for (int c2 = 0; c2 < 8; c2++) {
            const int rowb = w * 64 + c2 * 8;
            gload_lds16(Bsrc + (size_t)(rowb + r8) * HH + k0 + gc * 8, &Bs[rowb][0]);
        }
        asm volatile("s_waitcnt vmcnt(0)" ::: "memory");
        __syncthreads();
        // 4 sub-steps of K=16; A/B operand: m/n = lane&31, k = l5*8 + j
        // -> 16B chunk index = ks*2 + l5, swizzled by row&7 (= lane&7)
#pragma unroll
        for (int ks = 0; ks < 4; ks++) {
            const int pch = ((ks * 2 + l5) ^ swr) * 8;
            v8bf a[2], b[4];
#pragma unroll
            for (int mi = 0; mi < 2; mi++)
                a[mi] = *(const v8bf*)&As[waveM * 64 + mi * 32 + l31][pch];
#pragma unroll
            for (int g = 0; g < 4; g++)
                b[g] = *(const v8bf*)&Bs[waveN * 128 + g * 32 + l31][pch];
#pragma unroll
            for (int mi = 0; mi < 2; mi++)
#pragma unroll
                for (int g = 0; g < 4; g++)
                    acc[mi][g] = __builtin_amdgcn_mfma_f32_32x32x16_bf16(
                        a[mi], b[g], acc[mi][g], 0, 0, 0);
        }
        __syncthreads();
    }

    // Epilogue. Lane holds gates i,f,g,o at:
    //   j     = jb2*64 + waveN*32 + l31            (one j per lane)
    //   batch = blockB + waveM*64 + mi*32 + s + 8*q + 4*l5,  reg = 4*q+s
    const int jj = jb2 * 64 + waveN * 32 + l31;
    float wih[4], bsv[4];
#pragma unroll
    for (int g = 0; g < 4; g++) {
        wih[g] = Wih[g * HH + jj];
        bsv[g] = bias[g * HH + jj];
    }
    const float wo = Wout[jj];

#pragma unroll
    for (int mi = 0; mi < 2; mi++) {
#pragma unroll
        for (int q = 0; q < 4; q++) {
#pragma unroll
            for (int s = 0; s < 4; s++) {
                const int reg = q * 4 + s;
                const int b = blockB + waveM * 64 + mi * 32 + s + 8 * q + 4 * l5;
                const float x = predbuf_r[b];  // pred_{t-1} (incl b_out) or 0
                const float gi = acc[mi][0][reg] + x * wih[0] + bsv[0];
                const float gf = acc[mi][1][reg] + x * wih[1] + bsv[1];
                const float gg = acc[mi][2][reg] + x * wih[2] + bsv[2];
                const float go = acc[mi][3][reg] + x * wih[3] + bsv[3];
                const float cn = fast_sigmoid(gf) * cin[(size_t)b * HH + jj]
                               + fast_sigmoid(gi) * fast_tanh(gg);
                cout[(size_t)b * HH + jj] = cn;
                const float hn = fast_sigmoid(go) * fast_tanh(cn);
                hwrite[(size_t)b * HH + jj] = (bf16)hn;
                // reduce h*wo over the 32 j-lanes sharing this batch row
                float p = hn * wo;
                p += __shfl_xor(p, 1);
                p += __shfl_xor(p, 2);
                p += __shfl_xor(p, 4);
                p += __shfl_xor(p, 8);
                p += __shfl_xor(p, 16);
                if (l31 == 0) atomicAdd(&predbuf_w[b], p);
            }
        }
    }
}

// ---- Output transpose: out[b][t] = pred_t[b] ------------------------------

__global__ void write_out(const float* __restrict__ predbuf, float* __restrict__ out) {
    int idx = blockIdx.x * blockDim.x + threadIdx.x;
    if (idx < BB * TT) {
        int t = idx & (TT - 1);
        int b = idx >> 7;
        out[idx] = predbuf[(size_t)(t + 1) * BB + b];
    }
}

// ---- Host launch -----------------------------------------------------------

extern "C" void kernel_launch(void* const* d_in, const int* in_sizes, int n_in,
                              void* d_out, int out_size, void* d_ws, size_t ws_size,
                              hipStream_t stream) {
    const float* hidden = (const float*)d_in[0];
    const float* cell   = (const float*)d_in[1];
    const float* Wih    = (const float*)d_in[2];
    const float* Whh    = (const float*)d_in[3];
    const float* bih    = (const float*)d_in[4];
    const float* bhh    = (const float*)d_in[5];
    const float* Wout   = (const float*)d_in[6];
    const float* bout   = (const float*)d_in[7];
    float* out = (float*)d_out;

    char* ws = (char*)d_ws;
    bf16* Wr = (bf16*)ws;        ws += (size_t)4 * HH * HH * 2;   // 8 MB
    bf16* hb0 = (bf16*)ws;       ws += (size_t)BB * HH * 2;       // 8 MB
    bf16* hb1 = (bf16*)ws;       ws += (size_t)BB * HH * 2;       // 8 MB
    float* cbuf = (float*)ws;    ws += (size_t)BB * HH * 4;       // 16 MB
    float* bias = (float*)ws;    ws += (size_t)4 * HH * 4;        // 16 KB
    float* predbuf = (float*)ws; ws += (size_t)(TT + 1) * BB * 4; // 2.1 MB

    prep_weights<<<(4 * HH * HH + 255) / 256, 256, 0, stream>>>(Whh, bih, bhh, Wr, bias);
    prep_h<<<(BB * HH + 255) / 256, 256, 0, stream>>>(hidden, hb0);
    prep_pred<<<((TT + 1) * BB + 255) / 256, 256, 0, stream>>>(predbuf, bout);

    bf16* hb[2] = {hb0, hb1};
    for (int t = 0; t < TT; t++) {
        const bf16* hr = hb[t & 1];
        bf16* hw = hb[(t + 1) & 1];
        const float* ci = (t == 0) ? cell : cbuf;
        lstm_step<<<512, 256, 0, stream>>>(
            hr, hw, ci, cbuf, Wr, bias, Wih, Wout,
            predbuf + (size_t)t * BB, predbuf + (size_t)(t + 1) * BB);
    }

    write_out<<<(BB * TT + 255) / 256, 256, 0, stream>>>(predbuf, out);
}

// Round 11
// 5867.305 us; speedup vs baseline: 1.2419x; 1.2419x over previous
//
#include <hip/hip_runtime.h>
#include <hip/hip_bf16.h>
#include <stdint.h>

// LSTM decoder: H=1024, B=4096, T=128, IN=1.
// R11 = R7 machinery (BKK=64, conflict-free 16-row XOR-swizzle reads,
// global_load_lds w16, vmcnt(0)+syncthreads) with BM=64 x BJ=64 tiles:
// 40 KB LDS -> 4 blocks/CU -> 16 waves/CU (R2's occupancy, R7's A-traffic).
// Wr rows [jb2][h][g][jj32] keep gates colocated per lane (R10 layout).
// XCD pinning: 2 jb2 per XCD (1 MB weights L2-resident across steps).

#define HH 1024
#define BB 4096
#define TT 128

#define BM 64    // batch rows per block
#define BKK 64   // K tile

typedef __bf16 bf16;
typedef __bf16 v8bf __attribute__((ext_vector_type(8)));
typedef float f32x4 __attribute__((ext_vector_type(4)));

__device__ __forceinline__ float fast_sigmoid(float x) {
    return 1.0f / (1.0f + __expf(-x));
}
__device__ __forceinline__ float fast_tanh(float x) {
    return 1.0f - 2.0f / (__expf(2.0f * x) + 1.0f);
}

__device__ __forceinline__ void gload_lds16(const void* g, void* l) {
    __builtin_amdgcn_global_load_lds(
        (const __attribute__((address_space(1))) uint32_t*)(uintptr_t)g,
        (__attribute__((address_space(3))) uint32_t*)(uint32_t)(uintptr_t)l,
        16, 0, 0);
}

// ---- Prologue kernels ------------------------------------------------------

// Wr row = jb2*256 + h*128 + g*32 + jj  <->  Whh row = g*HH + jb2*64 + h*32 + jj
__global__ void prep_weights(const float* __restrict__ Whh,
                             const float* __restrict__ bih,
                             const float* __restrict__ bhh,
                             bf16* __restrict__ Wr,
                             float* __restrict__ bias) {
    int idx = blockIdx.x * blockDim.x + threadIdx.x;
    if (idx < 4 * HH * HH) {
        int k   = idx & (HH - 1);
        int row = idx >> 10;
        int jb2 = row >> 8;
        int h   = (row >> 7) & 1;
        int g   = (row >> 5) & 3;
        int jj  = row & 31;
        int srow = g * HH + jb2 * 64 + h * 32 + jj;
        Wr[idx] = (bf16)Whh[srow * HH + k];
    }
    if (idx < 4 * HH) bias[idx] = bih[idx] + bhh[idx];
}

__global__ void prep_h(const float* __restrict__ h0, bf16* __restrict__ hb) {
    int idx = blockIdx.x * blockDim.x + threadIdx.x;
    if (idx < BB * HH) hb[idx] = (bf16)h0[idx];
}

__global__ void prep_pred(float* __restrict__ predbuf, const float* __restrict__ b_out) {
    int idx = blockIdx.x * blockDim.x + threadIdx.x;
    if (idx < (TT + 1) * BB) predbuf[idx] = (idx < BB) ? 0.0f : b_out[0];
}

// ---- Per-step fused GEMM + cell update ------------------------------------
// 1024 blocks = 16 jb2 x 64 bb. Block tile: 64 batch x 256 weight rows.
// Wave (waveM, waveN): 32 batch x 128 wrows (j-half waveN: 4 gates x 32 j).
// acc[mi][g*2+jh]: gates colocated at (batch, j), same epilogue as R7.

__global__ __launch_bounds__(256, 4)
void lstm_step(const bf16* __restrict__ hread, bf16* __restrict__ hwrite,
               const float* __restrict__ cin, float* __restrict__ cout,
               const bf16* __restrict__ Wr, const float* __restrict__ bias,
               const float* __restrict__ Wih, const float* __restrict__ Wout,
               const float* __restrict__ predbuf_r, float* __restrict__ predbuf_w) {
    // unpadded 128-B rows, XOR-swizzled: phys 16B-chunk = logical ^ (row&7)
    __shared__ bf16 As[BM][BKK];        // h tile: 64 x 64        (8 KB)
    __shared__ bf16 Bs[4 * BM][BKK];    // weights: 256 x 64      (32 KB)

    const int tid   = threadIdx.x;
    const int lane  = tid & 63;
    const int w     = tid >> 6;
    const int waveM = w >> 1, waveN = w & 1;
    const int quad  = lane >> 4, l15 = lane & 15;

    // XCD pinning: XCD x = bid&7 hosts jb2 in {2x, 2x+1} (1 MB weights).
    const int bid = blockIdx.x;
    const int i   = bid >> 3;
    const int jb2 = (bid & 7) * 2 + (i & 1);  // 0..15
    const int bb  = i >> 1;                   // 0..63
    const int blockB = bb * BM;

    const bf16* Asrc = hread + (size_t)blockB * HH;
    const bf16* Bsrc = Wr + (size_t)jb2 * 256 * HH;

    const int r8  = lane >> 3;        // 0..7 (staging row-in-group)
    const int gc  = (lane & 7) ^ r8;  // staging swizzled global chunk
    const int swr = l15 & 7;          // read-side swizzle key (row & 7)

    // epilogue constants; bias folded into acc init
    float wihv[2][4], bsvv[2][4], wov[2];
#pragma unroll
    for (int jh = 0; jh < 2; jh++) {
        const int j = jb2 * 64 + waveN * 32 + jh * 16 + l15;
#pragma unroll
        for (int g = 0; g < 4; g++) {
            wihv[jh][g] = Wih[g * HH + j];
            bsvv[jh][g] = bias[g * HH + j];
        }
        wov[jh] = Wout[j];
    }

    f32x4 acc[2][8]; // [m-tile][gate*2 + j-half], bias-initialized
#pragma unroll
    for (int mi = 0; mi < 2; mi++)
#pragma unroll
        for (int g = 0; g < 4; g++)
#pragma unroll
            for (int jh = 0; jh < 2; jh++) {
                const float bv = bsvv[jh][g];
                acc[mi][g * 2 + jh] = (f32x4){bv, bv, bv, bv};
            }

    for (int k0 = 0; k0 < HH; k0 += BKK) {
        // A: 64 rows; wave stages [w*16, w*16+16) — 2 calls (8 rows x 128 B)
#pragma unroll
        for (int c2 = 0; c2 < 2; c2++) {
            const int rowb = w * 16 + c2 * 8;
            gload_lds16(Asrc + (size_t)(rowb + r8) * HH + k0 + gc * 8, &As[rowb][0]);
        }
        // B: 256 rows; wave stages [w*64, w*64+64) — 8 calls
#pragma unroll
        for (int c2 = 0; c2 < 8; c2++) {
            const int rowb = w * 64 + c2 * 8;
            gload_lds16(Bsrc + (size_t)(rowb + r8) * HH + k0 + gc * 8, &Bs[rowb][0]);
        }
        asm volatile("s_waitcnt vmcnt(0)" ::: "memory");
        __syncthreads();
#pragma unroll
        for (int kk = 0; kk < 2; kk++) {
            const int pch = ((kk * 4 + quad) ^ swr) * 8;
            v8bf a[2];
#pragma unroll
            for (int mi = 0; mi < 2; mi++)
                a[mi] = *(const v8bf*)&As[waveM * 32 + mi * 16 + l15][pch];
#pragma unroll
            for (int g = 0; g < 4; g++) {
                v8bf b0 = *(const v8bf*)&Bs[waveN * 128 + g * 32 + l15][pch];
                v8bf b1 = *(const v8bf*)&Bs[waveN * 128 + g * 32 + 16 + l15][pch];
#pragma unroll
                for (int mi = 0; mi < 2; mi++) {
                    acc[mi][g * 2 + 0] = __builtin_amdgcn_mfma_f32_16x16x32_bf16(
                        a[mi], b0, acc[mi][g * 2 + 0], 0, 0, 0);
                    acc[mi][g * 2 + 1] = __builtin_amdgcn_mfma_f32_16x16x32_bf16(
                        a[mi], b1, acc[mi][g * 2 + 1], 0, 0, 0);
                }
            }
        }
        __syncthreads();
    }

    // Epilogue: acc[mi][g*2+jh][r] = gate g (bias included) at (batch, j):
    //   batch = blockB + waveM*32 + mi*16 + quad*4 + r
    //   j     = jb2*64 + waveN*32 + jh*16 + l15
#pragma unroll
    for (int mi = 0; mi < 2; mi++) {
#pragma unroll
        for (int r = 0; r < 4; r++) {
            const int b = blockB + waveM * 32 + mi * 16 + quad * 4 + r;
            const float x = predbuf_r[b];  // pred_{t-1} (incl. b_out) or 0 at t=0
            float pacc = 0.0f;
#pragma unroll
            for (int jh = 0; jh < 2; jh++) {
                const int j = jb2 * 64 + waveN * 32 + jh * 16 + l15;
                const float gi = acc[mi][0 + jh][r] + x * wihv[jh][0];
                const float gf = acc[mi][2 + jh][r] + x * wihv[jh][1];
                const float gg = acc[mi][4 + jh][r] + x * wihv[jh][2];
                const float go = acc[mi][6 + jh][r] + x * wihv[jh][3];
                const float cn = fast_sigmoid(gf) * cin[(size_t)b * HH + j]
                               + fast_sigmoid(gi) * fast_tanh(gg);
                cout[(size_t)b * HH + j] = cn;
                const float hn = fast_sigmoid(go) * fast_tanh(cn);
                hwrite[(size_t)b * HH + j] = (bf16)hn;
                pacc += hn * wov[jh];
            }
            pacc += __shfl_xor(pacc, 1);
            pacc += __shfl_xor(pacc, 2);
            pacc += __shfl_xor(pacc, 4);
            pacc += __shfl_xor(pacc, 8);
            if (l15 == 0) atomicAdd(&predbuf_w[b], pacc);
        }
    }
}

// ---- Output transpose: out[b][t] = pred_t[b] ------------------------------

__global__ void write_out(const float* __restrict__ predbuf, float* __restrict__ out) {
    int idx = blockIdx.x * blockDim.x + threadIdx.x;
    if (idx < BB * TT) {
        int t = idx & (TT - 1);
        int b = idx >> 7;
        out[idx] = predbuf[(size_t)(t + 1) * BB + b];
    }
}

// ---- Host launch -----------------------------------------------------------

extern "C" void kernel_launch(void* const* d_in, const int* in_sizes, int n_in,
                              void* d_out, int out_size, void* d_ws, size_t ws_size,
                              hipStream_t stream) {
    const float* hidden = (const float*)d_in[0];
    const float* cell   = (const float*)d_in[1];
    const float* Wih    = (const float*)d_in[2];
    const float* Whh    = (const float*)d_in[3];
    const float* bih    = (const float*)d_in[4];
    const float* bhh    = (const float*)d_in[5];
    const float* Wout   = (const float*)d_in[6];
    const float* bout   = (const float*)d_in[7];
    float* out = (float*)d_out;

    char* ws = (char*)d_ws;
    bf16* Wr = (bf16*)ws;        ws += (size_t)4 * HH * HH * 2;   // 8 MB
    bf16* hb0 = (bf16*)ws;       ws += (size_t)BB * HH * 2;       // 8 MB
    bf16* hb1 = (bf16*)ws;       ws += (size_t)BB * HH * 2;       // 8 MB
    float* cbuf = (float*)ws;    ws += (size_t)BB * HH * 4;       // 16 MB
    float* bias = (float*)ws;    ws += (size_t)4 * HH * 4;        // 16 KB
    float* predbuf = (float*)ws; ws += (size_t)(TT + 1) * BB * 4; // 2.1 MB

    prep_weights<<<(4 * HH * HH + 255) / 256, 256, 0, stream>>>(Whh, bih, bhh, Wr, bias);
    prep_h<<<(BB * HH + 255) / 256, 256, 0, stream>>>(hidden, hb0);
    prep_pred<<<((TT + 1) * BB + 255) / 256, 256, 0, stream>>>(predbuf, bout);

    bf16* hb[2] = {hb0, hb1};
    for (int t = 0; t < TT; t++) {
        const bf16* hr = hb[t & 1];
        bf16* hw = hb[(t + 1) & 1];
        const float* ci = (t == 0) ? cell : cbuf;
        lstm_step<<<16 * (BB / BM), 256, 0, stream>>>(
            hr, hw, ci, cbuf, Wr, bias, Wih, Wout,
            predbuf + (size_t)t * BB, predbuf + (size_t)(t + 1) * BB);
    }

    write_out<<<(BB * TT + 255) / 256, 256, 0, stream>>>(predbuf, out);
}

// Round 12
// 5344.162 us; speedup vs baseline: 1.3635x; 1.0979x over previous
//
#include <hip/hip_runtime.h>
#include <hip/hip_bf16.h>
#include <stdint.h>

// LSTM decoder: H=1024, B=4096, T=128, IN=1.
// R12 = R7 core (BM=128 x BJ=64 tile, BKK=64, conflict-free XOR swizzle,
// global_load_lds w16, vmcnt(0)+syncthreads, XCD-grouped jb2) +
//  - pred feedback folded into weights: for t>=1,
//      gates = (Whh + Wih (x) Wout) h + (b + Wih*b_out)   [exact rank-1 fold]
//    t=0 uses the unfolded copy (x0 = 0). Epilogue no longer reads pred.
//  - cell state kept in bf16 (in-place buffer): halves c traffic.

#define HH 1024
#define BB 4096
#define TT 128

#define BM 128   // batch rows per block
#define BKK 64   // K tile

typedef __bf16 bf16;
typedef __bf16 v8bf __attribute__((ext_vector_type(8)));
typedef float f32x4 __attribute__((ext_vector_type(4)));

__device__ __forceinline__ float fast_sigmoid(float x) {
    return 1.0f / (1.0f + __expf(-x));
}
__device__ __forceinline__ float fast_tanh(float x) {
    return 1.0f - 2.0f / (__expf(2.0f * x) + 1.0f);
}

__device__ __forceinline__ void gload_lds16(const void* g, void* l) {
    __builtin_amdgcn_global_load_lds(
        (const __attribute__((address_space(1))) uint32_t*)(uintptr_t)g,
        (__attribute__((address_space(3))) uint32_t*)(uint32_t)(uintptr_t)l,
        16, 0, 0);
}

// ---- Prologue kernels ------------------------------------------------------

// Wr row layout: jb2*256 + g*64 + jj  <->  Whh row g*HH + jb2*64 + jj
// Wr0 = pure Whh (for t=0); Wr1 = Whh + Wih (x) Wout (for t>=1).
__global__ void prep_weights(const float* __restrict__ Whh,
                             const float* __restrict__ bih,
                             const float* __restrict__ bhh,
                             const float* __restrict__ Wih,
                             const float* __restrict__ Wout,
                             const float* __restrict__ bout,
                             bf16* __restrict__ Wr0, bf16* __restrict__ Wr1,
                             float* __restrict__ bias0, float* __restrict__ bias1) {
    int idx = blockIdx.x * blockDim.x + threadIdx.x;
    if (idx < 4 * HH * HH) {
        int k   = idx & (HH - 1);
        int row = idx >> 10;
        int jb2 = row >> 8;
        int g   = (row >> 6) & 3;
        int jj  = row & 63;
        int srow = g * HH + jb2 * 64 + jj;
        float wv = Whh[srow * HH + k];
        Wr0[idx] = (bf16)wv;
        Wr1[idx] = (bf16)(wv + Wih[srow] * Wout[k]);
    }
    if (idx < 4 * HH) {
        float b = bih[idx] + bhh[idx];
        bias0[idx] = b;
        bias1[idx] = b + Wih[idx] * bout[0];
    }
}

__global__ void prep_h(const float* __restrict__ h0, bf16* __restrict__ hb) {
    int idx = blockIdx.x * blockDim.x + threadIdx.x;
    if (idx < BB * HH) hb[idx] = (bf16)h0[idx];
}

__global__ void prep_c(const float* __restrict__ c0, bf16* __restrict__ cb) {
    int idx = blockIdx.x * blockDim.x + threadIdx.x;
    if (idx < BB * HH) cb[idx] = (bf16)c0[idx];
}

// all pred slots = b_out; atomics add the raw dot on top
__global__ void prep_pred(float* __restrict__ predbuf, const float* __restrict__ b_out) {
    int idx = blockIdx.x * blockDim.x + threadIdx.x;
    if (idx < (TT + 1) * BB) predbuf[idx] = b_out[0];
}

// ---- Per-step fused GEMM + cell update ------------------------------------
// 512 blocks = 16 jb2 x 32 bb. Block tile: 128 batch x 256 weight rows.
// Wave (waveM, waveN): 64 batch x 128 wrows; acc[mi][g*2+jh].

__global__ __launch_bounds__(256, 2)
void lstm_step(const bf16* __restrict__ hread, bf16* __restrict__ hwrite,
               bf16* __restrict__ cbuf,
               const bf16* __restrict__ Wr, const float* __restrict__ biasp,
               const float* __restrict__ Wout, float* __restrict__ predbuf_w) {
    // unpadded 128-B rows, XOR-swizzled: phys 16B-chunk = logical ^ (row&7)
    __shared__ bf16 As[BM][BKK];        // h tile: 128 x 64      (16 KB)
    __shared__ bf16 Bs[2 * BM][BKK];    // weights: 256 x 64     (32 KB)

    const int tid   = threadIdx.x;
    const int lane  = tid & 63;
    const int w     = tid >> 6;
    const int waveM = w >> 1, waveN = w & 1;
    const int quad  = lane >> 4, l15 = lane & 15;

    const int bid    = blockIdx.x;
    const int jb2    = (bid & 7) * 2 + ((bid >> 3) & 1); // 0..15, XCD-grouped
    const int blockB = (bid >> 4) * BM;                  // batch base

    const bf16* Asrc = hread + (size_t)blockB * HH;
    const bf16* Bsrc = Wr + (size_t)jb2 * 256 * HH;

    const int r8  = lane >> 3;        // 0..7
    const int gc  = (lane & 7) ^ r8;  // swizzled global 16B-chunk for staging
    const int swr = l15 & 7;          // read-side swizzle key (row & 7)

    // epilogue constants; bias folded into acc init
    float bsvv[2][4], wov[2];
#pragma unroll
    for (int jh = 0; jh < 2; jh++) {
        const int j = jb2 * 64 + waveN * 32 + jh * 16 + l15;
#pragma unroll
        for (int g = 0; g < 4; g++) bsvv[jh][g] = biasp[g * HH + j];
        wov[jh] = Wout[j];
    }

    f32x4 acc[4][8]; // [m-tile][gate*2 + j-half], bias-initialized
#pragma unroll
    for (int mi = 0; mi < 4; mi++)
#pragma unroll
        for (int g = 0; g < 4; g++)
#pragma unroll
            for (int jh = 0; jh < 2; jh++) {
                const float bv = bsvv[jh][g];
                acc[mi][g * 2 + jh] = (f32x4){bv, bv, bv, bv};
            }

    for (int k0 = 0; k0 < HH; k0 += BKK) {
        // A: wave stages rows [w*32, w*32+32) — 4 calls (8 rows x 128 B each)
#pragma unroll
        for (int c2 = 0; c2 < 4; c2++) {
            const int rowb = w * 32 + c2 * 8;
            gload_lds16(Asrc + (size_t)(rowb + r8) * HH + k0 + gc * 8, &As[rowb][0]);
        }
        // B: wave stages rows [w*64, w*64+64) — 8 calls
#pragma unroll
        for (int c2 = 0; c2 < 8; c2++) {
            const int rowb = w * 64 + c2 * 8;
            gload_lds16(Bsrc + (size_t)(rowb + r8) * HH + k0 + gc * 8, &Bs[rowb][0]);
        }
        asm volatile("s_waitcnt vmcnt(0)" ::: "memory");
        __syncthreads();
#pragma unroll
        for (int kk = 0; kk < 2; kk++) {
            v8bf a[4], b[8];
            const int pch = ((kk * 4 + quad) ^ swr) * 8;
#pragma unroll
            for (int mi = 0; mi < 4; mi++)
                a[mi] = *(const v8bf*)&As[waveM * 64 + mi * 16 + l15][pch];
#pragma unroll
            for (int g = 0; g < 4; g++)
#pragma unroll
                for (int jh = 0; jh < 2; jh++)
                    b[g * 2 + jh] =
                        *(const v8bf*)&Bs[g * 64 + waveN * 32 + jh * 16 + l15][pch];
#pragma unroll
            for (int mi = 0; mi < 4; mi++)
#pragma unroll
                for (int nt = 0; nt < 8; nt++)
                    acc[mi][nt] = __builtin_amdgcn_mfma_f32_16x16x32_bf16(
                        a[mi], b[nt], acc[mi][nt], 0, 0, 0);
        }
        __syncthreads();
    }

    // Epilogue: acc[mi][g*2+jh][r] = gate g (bias incl.) at (batch, j):
    //   batch = blockB + waveM*64 + mi*16 + quad*4 + r
    //   j     = jb2*64 + waveN*32 + jh*16 + l15
#pragma unroll
    for (int mi = 0; mi < 4; mi++) {
#pragma unroll
        for (int r = 0; r < 4; r++) {
            const int b = blockB + waveM * 64 + mi * 16 + quad * 4 + r;
            float pacc = 0.0f;
#pragma unroll
            for (int jh = 0; jh < 2; jh++) {
                const int j = jb2 * 64 + waveN * 32 + jh * 16 + l15;
                const float gi = acc[mi][0 + jh][r];
                const float gf = acc[mi][2 + jh][r];
                const float gg = acc[mi][4 + jh][r];
                const float go = acc[mi][6 + jh][r];
                const float cprev = (float)cbuf[(size_t)b * HH + j];
                const float cn = fast_sigmoid(gf) * cprev
                               + fast_sigmoid(gi) * fast_tanh(gg);
                cbuf[(size_t)b * HH + j] = (bf16)cn;   // in-place, 1 owner/elem
                const float hn = fast_sigmoid(go) * fast_tanh(cn);
                hwrite[(size_t)b * HH + j] = (bf16)hn;
                pacc += hn * wov[jh];
            }
            pacc += __shfl_xor(pacc, 1);
            pacc += __shfl_xor(pacc, 2);
            pacc += __shfl_xor(pacc, 4);
            pacc += __shfl_xor(pacc, 8);
            if (l15 == 0) atomicAdd(&predbuf_w[b], pacc);
        }
    }
}

// ---- Output transpose: out[b][t] = pred_t[b] ------------------------------

__global__ void write_out(const float* __restrict__ predbuf, float* __restrict__ out) {
    int idx = blockIdx.x * blockDim.x + threadIdx.x;
    if (idx < BB * TT) {
        int t = idx & (TT - 1);
        int b = idx >> 7;
        out[idx] = predbuf[(size_t)(t + 1) * BB + b];
    }
}

// ---- Host launch -----------------------------------------------------------

extern "C" void kernel_launch(void* const* d_in, const int* in_sizes, int n_in,
                              void* d_out, int out_size, void* d_ws, size_t ws_size,
                              hipStream_t stream) {
    const float* hidden = (const float*)d_in[0];
    const float* cell   = (const float*)d_in[1];
    const float* Wih    = (const float*)d_in[2];
    const float* Whh    = (const float*)d_in[3];
    const float* bih    = (const float*)d_in[4];
    const float* bhh    = (const float*)d_in[5];
    const float* Wout   = (const float*)d_in[6];
    const float* bout   = (const float*)d_in[7];
    float* out = (float*)d_out;

    char* ws = (char*)d_ws;
    bf16* Wr0 = (bf16*)ws;       ws += (size_t)4 * HH * HH * 2;   // 8 MB
    bf16* Wr1 = (bf16*)ws;       ws += (size_t)4 * HH * HH * 2;   // 8 MB
    bf16* hb0 = (bf16*)ws;       ws += (size_t)BB * HH * 2;       // 8 MB
    bf16* hb1 = (bf16*)ws;       ws += (size_t)BB * HH * 2;       // 8 MB
    bf16* cbuf = (bf16*)ws;      ws += (size_t)BB * HH * 2;       // 8 MB
    float* bias0 = (float*)ws;   ws += (size_t)4 * HH * 4;        // 16 KB
    float* bias1 = (float*)ws;   ws += (size_t)4 * HH * 4;        // 16 KB
    float* predbuf = (float*)ws; ws += (size_t)(TT + 1) * BB * 4; // 2.1 MB

    prep_weights<<<(4 * HH * HH + 255) / 256, 256, 0, stream>>>(
        Whh, bih, bhh, Wih, Wout, bout, Wr0, Wr1, bias0, bias1);
    prep_h<<<(BB * HH + 255) / 256, 256, 0, stream>>>(hidden, hb0);
    prep_c<<<(BB * HH + 255) / 256, 256, 0, stream>>>(cell, cbuf);
    prep_pred<<<((TT + 1) * BB + 255) / 256, 256, 0, stream>>>(predbuf, bout);

    bf16* hb[2] = {hb0, hb1};
    for (int t = 0; t < TT; t++) {
        const bf16* hr = hb[t & 1];
        bf16* hw = hb[(t + 1) & 1];
        const bf16* Wr   = (t == 0) ? Wr0 : Wr1;
        const float* bsp = (t == 0) ? bias0 : bias1;
        lstm_step<<<512, 256, 0, stream>>>(
            hr, hw, cbuf, Wr, bsp, Wout, predbuf + (size_t)(t + 1) * BB);
    }

    write_out<<<(BB * TT + 255) / 256, 256, 0, stream>>>(predbuf, out);
}